// Round 1
// baseline (475.049 us; speedup 1.0000x reference)
//
#include <hip/hip_runtime.h>

// ---------------------------------------------------------------------------
// GridNet fused forward: MLP (bf16 MFMA) + softmax + 5x5 gather + sigmoid
// B=262144, GS=(1024,2048), NS=5, layers 2-64-256-512-256-64-75
// ---------------------------------------------------------------------------

#define PI_F     3.14159265358979323846f
#define TWO_PI_F 6.28318530717958647692f

typedef __attribute__((ext_vector_type(8))) short bf16x8;   // 8 bf16 = 4 VGPRs
typedef __attribute__((ext_vector_type(4))) float f32x4;    // MFMA C/D frag

__device__ __forceinline__ short f2bf(float f) {
    unsigned u = __builtin_bit_cast(unsigned, f);
    u += 0x7fffu + ((u >> 16) & 1u);            // round-nearest-even
    return (short)(u >> 16);
}

// ws layout (in shorts):
//  Wt2 [256][64]   @ 0
//  Wt3 [512][256]  @ 16384
//  Wt4 [256][512]  @ 147456
//  Wt5 [64][256]   @ 278528
//  Wt6 [80][64]    @ 294912   (rows 75..79 zero-padded)
//  b6pad 80 floats @ 300032   (entries 75..79 = 0)
#define WT2_OFF 0
#define WT3_OFF 16384
#define WT4_OFF 147456
#define WT5_OFF 278528
#define WT6_OFF 294912
#define B6_OFF  300032
#define PREP_TOTAL (300032 + 80)

__global__ void prep_weights(const float* __restrict__ w2, const float* __restrict__ w3,
                             const float* __restrict__ w4, const float* __restrict__ w5,
                             const float* __restrict__ w6, const float* __restrict__ b6,
                             short* __restrict__ ws) {
    int idx = blockIdx.x * blockDim.x + threadIdx.x;
    if (idx >= PREP_TOTAL) return;
    if (idx >= 300032) {                         // padded bias6 as float
        int n = idx - 300032;
        ((float*)(ws + B6_OFF))[n] = (n < 75) ? b6[n] : 0.0f;
        return;
    }
    float v;
    if (idx < WT3_OFF) {        // Wt2: [n<256][k<64] <- w2[k][n] (64x256)
        int i = idx - WT2_OFF; int n = i >> 6, k = i & 63;
        v = w2[k * 256 + n];
    } else if (idx < WT4_OFF) { // Wt3: [n<512][k<256] <- w3[k][n] (256x512)
        int i = idx - WT3_OFF; int n = i >> 8, k = i & 255;
        v = w3[k * 512 + n];
    } else if (idx < WT5_OFF) { // Wt4: [n<256][k<512] <- w4[k][n] (512x256)
        int i = idx - WT4_OFF; int n = i >> 9, k = i & 511;
        v = w4[k * 256 + n];
    } else if (idx < WT6_OFF) { // Wt5: [n<64][k<256] <- w5[k][n] (256x64)
        int i = idx - WT5_OFF; int n = i >> 8, k = i & 255;
        v = w5[k * 64 + n];
    } else {                    // Wt6: [n<80][k<64] <- w6[k][n] (64x75), zero pad
        int i = idx - WT6_OFF; int n = i >> 6, k = i & 63;
        v = (n < 75) ? w6[k * 75 + n] : 0.0f;
    }
    ws[idx] = f2bf(v);
}

// One MFMA layer: out[m][n] = act(in[m][:] @ W + b),  W given transposed [N][K] bf16.
// Mtile = 64 rows in LDS. 8 waves split as MG m-groups x NG n-groups.
// A-frag: lane holds A[m=lane&15][k=(lane>>4)*8+j] -> ds_read_b128 from LDS (stride sIn).
// B-frag: lane holds B[k=(lane>>4)*8+j][n=lane&15] -> global 16B load from Wt[n][k].
// D: col = lane&15, row = (lane>>4)*4 + reg.
template<int K, int N, int MG, int NG, bool RELU, bool OUTF32>
__device__ __forceinline__ void mlp_layer(const short* __restrict__ aIn, const int sIn,
                                          void* outP, const int sOut,
                                          const short* __restrict__ Wt,
                                          const float* __restrict__ bias,
                                          int wave, int lane) {
    constexpr int MT = 4 / MG;          // 16-row m-tiles per wave
    constexpr int NT = (N / 16) / NG;   // 16-col n-tiles per wave
    if (wave >= MG * NG) return;
    const int mg = wave / NG, ng = wave % NG;
    const int mb = mg * MT * 16, nb = ng * NT * 16;
    const int lr = lane & 15, lq = lane >> 4;

    f32x4 acc[MT][NT];
    #pragma unroll
    for (int j = 0; j < NT; ++j) {
        float bv = bias[nb + j * 16 + lr];
        #pragma unroll
        for (int i = 0; i < MT; ++i) { acc[i][j] = (f32x4){bv, bv, bv, bv}; }
    }

    #pragma unroll
    for (int k0 = 0; k0 < K; k0 += 32) {
        bf16x8 a[MT], b[NT];
        #pragma unroll
        for (int i = 0; i < MT; ++i)
            a[i] = *(const bf16x8*)(aIn + (mb + i * 16 + lr) * sIn + k0 + lq * 8);
        #pragma unroll
        for (int j = 0; j < NT; ++j)
            b[j] = *(const bf16x8*)(Wt + (nb + j * 16 + lr) * K + k0 + lq * 8);
        #pragma unroll
        for (int i = 0; i < MT; ++i) {
            #pragma unroll
            for (int j = 0; j < NT; ++j)
                acc[i][j] = __builtin_amdgcn_mfma_f32_16x16x32_bf16(a[i], b[j], acc[i][j], 0, 0, 0);
        }
    }

    #pragma unroll
    for (int i = 0; i < MT; ++i) {
        #pragma unroll
        for (int j = 0; j < NT; ++j) {
            const int col  = nb + j * 16 + lr;
            const int rowb = mb + i * 16 + lq * 4;
            #pragma unroll
            for (int r = 0; r < 4; ++r) {
                float v = acc[i][j][r];
                if (RELU) v = fmaxf(v, 0.0f);
                if (OUTF32) ((float*)outP)[(rowb + r) * sOut + col] = v;
                else        ((short*)outP)[(rowb + r) * sOut + col] = f2bf(v);
            }
        }
    }
}

__global__ __launch_bounds__(512, 2) void gridnet_fused(
    const float* __restrict__ pos, const float* __restrict__ grid_pos,
    const float* __restrict__ w1, const float* __restrict__ b1,
    const float* __restrict__ b2, const float* __restrict__ b3,
    const float* __restrict__ b4, const float* __restrict__ b5,
    const short* __restrict__ ws, float* __restrict__ out) {

    __shared__ short ldsA[64 * 520];     // 66560 B: h1(72), h3(520), h5(72)
    __shared__ short ldsB[64 * 264];     // 33792 B: h2(264), h4(264)
    __shared__ float posS[64 * 2];
    __shared__ float logitsS[64 * 80];   // 20480 B

    const int tid  = threadIdx.x;
    const int wave = tid >> 6;
    const int lane = tid & 63;
    const int m0   = blockIdx.x * 64;

    if (tid < 128) posS[tid] = pos[m0 * 2 + tid];
    __syncthreads();

    // ---- layer 1 (2 -> 64), VALU ----
    #pragma unroll
    for (int r = 0; r < 8; ++r) {
        int idx = tid + r * 512;          // 64 pts x 64 outs
        int m = idx >> 6, n = idx & 63;
        float v = posS[m * 2 + 0] * w1[n] + posS[m * 2 + 1] * w1[64 + n] + b1[n];
        ldsA[m * 72 + n] = f2bf(fmaxf(v, 0.0f));
    }
    __syncthreads();

    mlp_layer< 64, 256, 1, 8, true,  false>(ldsA,  72, ldsB, 264, ws + WT2_OFF, b2, wave, lane);
    __syncthreads();
    mlp_layer<256, 512, 1, 8, true,  false>(ldsB, 264, ldsA, 520, ws + WT3_OFF, b3, wave, lane);
    __syncthreads();
    mlp_layer<512, 256, 1, 8, true,  false>(ldsA, 520, ldsB, 264, ws + WT4_OFF, b4, wave, lane);
    __syncthreads();
    mlp_layer<256,  64, 2, 4, true,  false>(ldsB, 264, ldsA,  72, ws + WT5_OFF, b5, wave, lane);
    __syncthreads();
    mlp_layer< 64,  80, 1, 5, false, true >(ldsA,  72, logitsS, 80, ws + WT6_OFF,
                                            (const float*)(ws + B6_OFF), wave, lane);
    __syncthreads();

    // ---- epilogue: softmax(75) + 5x5x3 gather + sigmoid, 8 lanes per point ----
    const int p = tid >> 3;              // point within tile
    const int s = tid & 7;               // sub-lane
    const float p0 = posS[p * 2 + 0], p1 = posS[p * 2 + 1];
    const int tx0 = (int)(p0 / PI_F * 1023.0f);                 // == int(gx), ix = tx0 + dy
    const int ty0 = (int)((p1 + PI_F) / TWO_PI_F * 2047.0f);    // == int(gy), iy = ty0 + dx

    const float* lrow = logitsS + p * 80;
    float lv[10];
    float mx = -1e30f;
    #pragma unroll
    for (int i = 0; i < 10; ++i) {
        int f = s + i * 8;
        float v = (f < 75) ? lrow[f] : -1e30f;
        lv[i] = v;
        mx = fmaxf(mx, v);
    }
    mx = fmaxf(mx, __shfl_xor(mx, 1, 8));
    mx = fmaxf(mx, __shfl_xor(mx, 2, 8));
    mx = fmaxf(mx, __shfl_xor(mx, 4, 8));

    float den = 0.0f, x0 = 0.0f, x1 = 0.0f, x2 = 0.0f;
    #pragma unroll
    for (int i = 0; i < 10; ++i) {
        int f = s + i * 8;
        if (f < 75) {
            float e = __expf(lv[i] - mx);
            den += e;
            int c = f / 25, rr = f % 25, dy = rr / 5, dx = rr % 5;
            float g = grid_pos[((tx0 + dy) * 2052 + (ty0 + dx)) * 3 + c];
            if      (c == 0) x0 += e * g;
            else if (c == 1) x1 += e * g;
            else             x2 += e * g;
        }
    }
    #pragma unroll
    for (int mask = 1; mask < 8; mask <<= 1) {
        den += __shfl_xor(den, mask, 8);
        x0  += __shfl_xor(x0,  mask, 8);
        x1  += __shfl_xor(x1,  mask, 8);
        x2  += __shfl_xor(x2,  mask, 8);
    }
    if (s < 3) {
        float xv = (s == 0) ? x0 : (s == 1 ? x1 : x2);
        xv /= den;
        float sig = 1.0f / (1.0f + __expf(-xv));
        out[(m0 + p) * 3 + s] = (sig > 0.1f) ? sig * 255.0f : 0.0f;
    }
}

extern "C" void kernel_launch(void* const* d_in, const int* in_sizes, int n_in,
                              void* d_out, int out_size, void* d_ws, size_t ws_size,
                              hipStream_t stream) {
    const float* pos      = (const float*)d_in[0];
    const float* grid_pos = (const float*)d_in[1];
    const float* w1 = (const float*)d_in[2];
    const float* b1 = (const float*)d_in[3];
    const float* w2 = (const float*)d_in[4];
    const float* b2 = (const float*)d_in[5];
    const float* w3 = (const float*)d_in[6];
    const float* b3 = (const float*)d_in[7];
    const float* w4 = (const float*)d_in[8];
    const float* b4 = (const float*)d_in[9];
    const float* w5 = (const float*)d_in[10];
    const float* b5 = (const float*)d_in[11];
    const float* w6 = (const float*)d_in[12];
    const float* b6 = (const float*)d_in[13];
    short* ws = (short*)d_ws;
    float* out = (float*)d_out;

    prep_weights<<<(PREP_TOTAL + 255) / 256, 256, 0, stream>>>(w2, w3, w4, w5, w6, b6, ws);
    gridnet_fused<<<262144 / 64, 512, 0, stream>>>(pos, grid_pos, w1, b1, b2, b3, b4, b5, ws, out);
}